// Round 1
// baseline (1223.370 us; speedup 1.0000x reference)
//
#include <hip/hip_runtime.h>
#include <stdint.h>

#define L_DIM 2048
#define B_DIM 32
#define D_DIM 1024
#define N_DIM 3072   // 3*D
#define K_DIM 1024
#define BD    32768  // B*D

typedef __bf16 bf16x8 __attribute__((ext_vector_type(8)));
typedef unsigned short ushort8 __attribute__((ext_vector_type(8)));
typedef float f32x4 __attribute__((ext_vector_type(4)));

static __device__ __forceinline__ unsigned short f2bf(float f) {
  unsigned u = __float_as_uint(f);
  u += 0x7FFFu + ((u >> 16) & 1u);   // RNE
  return (unsigned short)(u >> 16);
}

// ---------- convert x chunk (f32) -> bf16, 8 elems/thread ----------
__global__ void k_convx(const float* __restrict__ x, unsigned short* __restrict__ xb, int n8) {
  int i = blockIdx.x * blockDim.x + threadIdx.x;
  if (i >= n8) return;
  const float4* p = reinterpret_cast<const float4*>(x) + (size_t)i * 2;
  float4 a = p[0], b = p[1];
  ushort8 o;
  o[0] = f2bf(a.x); o[1] = f2bf(a.y); o[2] = f2bf(a.z); o[3] = f2bf(a.w);
  o[4] = f2bf(b.x); o[5] = f2bf(b.y); o[6] = f2bf(b.z); o[7] = f2bf(b.w);
  reinterpret_cast<ushort8*>(xb)[i] = o;
}

// ---------- W (K,N) f32 -> W^T (N,K) bf16 ----------
__global__ void k_wt(const float* __restrict__ w, unsigned short* __restrict__ wt) {
  int i = blockIdx.x * blockDim.x + threadIdx.x;
  if (i >= N_DIM * K_DIM) return;
  int n = i >> 10;          // /K_DIM
  int k = i & (K_DIM - 1);
  wt[i] = f2bf(w[(size_t)k * N_DIM + n]);
}

// ---------- per-column bias: col j=3d+k -> {0, fb[d], rb[d]} ----------
__global__ void k_biascol(const float* __restrict__ bias, float* __restrict__ bc) {
  int j = blockIdx.x * blockDim.x + threadIdx.x;
  if (j >= N_DIM) return;
  int d = j / 3;
  int k = j - 3 * d;
  float v = 0.f;
  if (k == 1) v = bias[d];
  else if (k == 2) v = bias[D_DIM + d];
  bc[j] = v;
}

// ---------- bf16 MFMA GEMM: C(M,3072) = A(M,1024) * W, 128x128 tile, BK=32 ----------
__global__ __launch_bounds__(256) void k_gemm(
    const unsigned short* __restrict__ A,   // (M, K) bf16, chunk
    const unsigned short* __restrict__ BT,  // (N, K) bf16 = W^T
    const float* __restrict__ bc,           // bias_col[N]
    float* __restrict__ C,                  // (M, N) f32, chunk
    int Mtiles)
{
  __shared__ unsigned short As[128 * 32];
  __shared__ unsigned short Bs[128 * 32];

  const int bx = blockIdx.x;
  const int bm = bx % Mtiles;
  const int bn = bx / Mtiles;
  const int t  = threadIdx.x;
  const int w  = t >> 6;          // wave 0..3
  const int l  = t & 63;
  const int wr = w >> 1, wc = w & 1;

  f32x4 acc[4][4];
#pragma unroll
  for (int i = 0; i < 4; ++i)
#pragma unroll
    for (int j = 0; j < 4; ++j) acc[i][j] = f32x4{0.f, 0.f, 0.f, 0.f};

  // staging: pass j in {0,1}: thread covers LDS elems [(j*256+t)*8, +8)
  const int srow = t >> 2;              // 0..63
  const int sk   = (t & 3) << 3;        // 0,8,16,24
  const unsigned short* ga = A  + (size_t)(bm * 128 + srow) * K_DIM + sk;
  const unsigned short* gb = BT + (size_t)(bn * 128 + srow) * K_DIM + sk;

  const int g = l >> 4;   // k-group 0..3
  const int r = l & 15;

  for (int kt = 0; kt < K_DIM / 32; ++kt) {
    if (kt) __syncthreads();
    const int ko = kt * 32;
    ushort8 a0 = *reinterpret_cast<const ushort8*>(ga + ko);
    ushort8 a1 = *reinterpret_cast<const ushort8*>(ga + (size_t)64 * K_DIM + ko);
    ushort8 b0 = *reinterpret_cast<const ushort8*>(gb + ko);
    ushort8 b1 = *reinterpret_cast<const ushort8*>(gb + (size_t)64 * K_DIM + ko);
    *reinterpret_cast<ushort8*>(&As[t * 8])        = a0;
    *reinterpret_cast<ushort8*>(&As[2048 + t * 8]) = a1;
    *reinterpret_cast<ushort8*>(&Bs[t * 8])        = b0;
    *reinterpret_cast<ushort8*>(&Bs[2048 + t * 8]) = b1;
    __syncthreads();

    bf16x8 af[4], bfr[4];
#pragma unroll
    for (int m = 0; m < 4; ++m) {
      int row = wr * 64 + m * 16 + r;
      af[m] = __builtin_bit_cast(bf16x8, *reinterpret_cast<const ushort8*>(&As[row * 32 + g * 8]));
    }
#pragma unroll
    for (int n = 0; n < 4; ++n) {
      int col = wc * 64 + n * 16 + r;
      bfr[n] = __builtin_bit_cast(bf16x8, *reinterpret_cast<const ushort8*>(&Bs[col * 32 + g * 8]));
    }
#pragma unroll
    for (int m = 0; m < 4; ++m)
#pragma unroll
      for (int n = 0; n < 4; ++n)
        acc[m][n] = __builtin_amdgcn_mfma_f32_16x16x32_bf16(af[m], bfr[n], acc[m][n], 0, 0, 0);
  }

  // epilogue: C/D layout col=lane&15, row=(lane>>4)*4+reg
  const int r4 = (l >> 4) * 4;
  const int cl = l & 15;
#pragma unroll
  for (int n = 0; n < 4; ++n) {
    int col = bn * 128 + wc * 64 + n * 16 + cl;
    float badd = bc[col];
#pragma unroll
    for (int m = 0; m < 4; ++m) {
      int row = bm * 128 + wr * 64 + m * 16 + r4;
      float* out = C + (size_t)row * N_DIM + col;
#pragma unroll
      for (int i = 0; i < 4; ++i)
        out[(size_t)i * N_DIM] = acc[m][n][i] + badd;
    }
  }
}

// ---------- SRU recurrence over a chunk of Lc steps ----------
__global__ void k_rec(const float* __restrict__ x,    // chunk base (Lc, BD)
                      const float* __restrict__ u3,   // chunk (Lc*BD*3)
                      const float* __restrict__ wcv,  // weight_c (2D)
                      const float* __restrict__ sxp,  // scale_x
                      float* __restrict__ c_state,    // (BD)
                      float* __restrict__ h,          // chunk base (Lc, BD)
                      int Lc)
{
  int tid = blockIdx.x * blockDim.x + threadIdx.x;
  if (tid >= BD) return;
  const int d = tid & (D_DIM - 1);
  const float fw = wcv[d];
  const float rw = wcv[D_DIM + d];
  const float sx = sxp[0];
  float c = c_state[tid];

  const float* u  = u3 + (size_t)tid * 3;
  const float* xp = x + tid;
  float*       hp = h + tid;

#pragma unroll 8
  for (int l = 0; l < Lc; ++l) {
    float u0 = u[0], u1 = u[1], u2 = u[2];
    float xv = xp[0] * sx;
    float f = 1.f / (1.f + __expf(-(u1 + c * fw)));
    float r = 1.f / (1.f + __expf(-(u2 + c * rw)));
    c = u0 + (c - u0) * f;
    hp[0] = xv + (c - xv) * r;
    u += (size_t)BD * 3;
    xp += BD;
    hp += BD;
  }
  c_state[tid] = c;
}

__global__ void k_copyc(const float* __restrict__ c_state, float* __restrict__ out) {
  int i = blockIdx.x * blockDim.x + threadIdx.x;
  if (i < BD) out[i] = c_state[i];
}

extern "C" void kernel_launch(void* const* d_in, const int* in_sizes, int n_in,
                              void* d_out, int out_size, void* d_ws, size_t ws_size,
                              hipStream_t stream) {
  const float* x    = (const float*)d_in[0];
  const float* w    = (const float*)d_in[1];
  const float* wcv  = (const float*)d_in[2];
  const float* bias = (const float*)d_in[3];
  const float* sx   = (const float*)d_in[4];
  float* hout = (float*)d_out;
  float* cout = hout + (size_t)L_DIM * BD;

  // workspace layout (ws_size-adaptive chunk of Lc timesteps)
  const size_t wt_bytes = (size_t)N_DIM * K_DIM * 2;      // 6,291,456
  const size_t bc_off   = wt_bytes;                       // bias_col (12,288 B)
  const size_t c_off    = bc_off + (size_t)N_DIM * 4;     // c_state (131,072 B)
  const size_t xbf_off  = c_off + (size_t)BD * 4;         // 6,434,816
  int Lc = 4;
  for (int cand : {512, 256, 128, 64, 32, 16, 8}) {
    size_t need = xbf_off + (size_t)cand * 65536 + (size_t)cand * 393216 + 1024;
    if (need <= ws_size) { Lc = cand; break; }
  }
  char* wsb = (char*)d_ws;
  unsigned short* wt_p  = (unsigned short*)wsb;
  float*          bc_p  = (float*)(wsb + bc_off);
  float*          c_p   = (float*)(wsb + c_off);
  unsigned short* xbf_p = (unsigned short*)(wsb + xbf_off);
  float*          u3_p  = (float*)(wsb + xbf_off + (size_t)Lc * 65536);

  hipMemsetAsync(c_p, 0, (size_t)BD * 4, stream);
  k_wt<<<(N_DIM * K_DIM) / 256, 256, 0, stream>>>(w, wt_p);
  k_biascol<<<(N_DIM + 255) / 256, 256, 0, stream>>>(bias, bc_p);

  const int nchunks = L_DIM / Lc;
  const int Mtiles  = (Lc * B_DIM) / 128;
  for (int ci = 0; ci < nchunks; ++ci) {
    const size_t base = (size_t)ci * Lc * BD;
    k_convx<<<(Lc * BD / 8 + 255) / 256, 256, 0, stream>>>(x + base, xbf_p, Lc * BD / 8);
    k_gemm<<<Mtiles * (N_DIM / 128), 256, 0, stream>>>(xbf_p, wt_p, bc_p, u3_p, Mtiles);
    k_rec<<<BD / 64, 64, 0, stream>>>(x + base, u3_p, wcv, sx, c_p, hout + base, Lc);
  }
  k_copyc<<<BD / 256, 256, 0, stream>>>(c_p, cout);
}

// Round 2
// 947.750 us; speedup vs baseline: 1.2908x; 1.2908x over previous
//
#include <hip/hip_runtime.h>
#include <stdint.h>

#define L_DIM 2048
#define B_DIM 32
#define D_DIM 1024
#define N_DIM 3072   // 3*D
#define K_DIM 1024
#define BD    32768  // B*D

typedef __bf16 bf16x8 __attribute__((ext_vector_type(8)));
typedef unsigned short ushort8 __attribute__((ext_vector_type(8)));
typedef float f32x4 __attribute__((ext_vector_type(4)));

typedef const __attribute__((address_space(1))) unsigned int* gq_t;
typedef __attribute__((address_space(3))) unsigned int* lq_t;

static __device__ __forceinline__ unsigned short f2bf(float f) {
  unsigned u = __float_as_uint(f);
  u += 0x7FFFu + ((u >> 16) & 1u);   // RNE
  return (unsigned short)(u >> 16);
}

static __device__ __forceinline__ float bf2f(unsigned short s) {
  return __uint_as_float(((unsigned)s) << 16);
}

// ---------- convert x chunk (f32) -> bf16, 8 elems/thread ----------
__global__ void k_convx(const float* __restrict__ x, unsigned short* __restrict__ xb, int n8) {
  int i = blockIdx.x * blockDim.x + threadIdx.x;
  if (i >= n8) return;
  const float4* p = reinterpret_cast<const float4*>(x) + (size_t)i * 2;
  float4 a = p[0], b = p[1];
  ushort8 o;
  o[0] = f2bf(a.x); o[1] = f2bf(a.y); o[2] = f2bf(a.z); o[3] = f2bf(a.w);
  o[4] = f2bf(b.x); o[5] = f2bf(b.y); o[6] = f2bf(b.z); o[7] = f2bf(b.w);
  reinterpret_cast<ushort8*>(xb)[i] = o;
}

// ---------- W (K,N=3072 interleaved 3d+k) f32 -> WT (N'=k*D+d, K) bf16 ----------
// LDS-tiled 64x64 transpose, plane-permuted output rows. grid = 16*16*3 = 768.
__global__ __launch_bounds__(256) void k_wt(const float* __restrict__ w, unsigned short* __restrict__ wt) {
  __shared__ unsigned short tile[64][65];
  const int bid = blockIdx.x;
  const int kb = bid & 15;          // K/64 tile
  const int db = (bid >> 4) & 15;   // D/64 tile
  const int kp = bid >> 8;          // plane 0..2
  const int t = threadIdx.x;
  const int c = t & 63;
  const int q = t >> 6;             // 0..3
#pragma unroll
  for (int i = 0; i < 16; ++i) {
    int r = q * 16 + i;             // k within tile
    float v = w[(size_t)(kb * 64 + r) * N_DIM + 3 * (db * 64 + c) + kp];
    tile[r][c] = f2bf(v);
  }
  __syncthreads();
  const int k = t & 63;
#pragma unroll
  for (int i = 0; i < 16; ++i) {
    int n = q * 16 + i;             // d within tile
    wt[(size_t)(kp * D_DIM + db * 64 + n) * K_DIM + kb * 64 + k] = tile[k][n];
  }
}

// ---------- per-column bias, plane layout: col j = k*D+d ----------
__global__ void k_biascol(const float* __restrict__ bias, float* __restrict__ bc) {
  int j = blockIdx.x * blockDim.x + threadIdx.x;
  if (j >= N_DIM) return;
  int k = j >> 10;
  int d = j & 1023;
  float v = 0.f;
  if (k == 1) v = bias[d];
  else if (k == 2) v = bias[D_DIM + d];
  bc[j] = v;
}

// ---------- bf16 MFMA GEMM, m97 structure: global_load_lds width-16 ----------
// C (M, 3072) bf16, plane cols. 128x128 tile, BK=32, 4 waves, 4x4 16x16 frags.
__global__ __launch_bounds__(256) void k_gemm(
    const unsigned short* __restrict__ A,   // (M, K) bf16 chunk
    const unsigned short* __restrict__ BT,  // (N', K) bf16 = permuted W^T
    const float* __restrict__ bc,           // bias_col[N']
    unsigned short* __restrict__ C,         // (M, N') bf16 chunk
    int Mtiles)
{
  __shared__ unsigned short As[128 * 32];
  __shared__ unsigned short Bs[128 * 32];

  const int bx = blockIdx.x;
  const int bm = bx % Mtiles;
  const int bn = bx / Mtiles;
  const int t  = threadIdx.x;
  const int l  = t & 63;
  const int w  = t >> 6;
  const int wr = w >> 1, wc = w & 1;

  f32x4 acc[4][4];
#pragma unroll
  for (int i = 0; i < 4; ++i)
#pragma unroll
    for (int j = 0; j < 4; ++j) acc[i][j] = f32x4{0.f, 0.f, 0.f, 0.f};

  // staging: inst i covers LDS bytes [(i*256+t)*16, +16) == element row (i*256+t)/4, k-chunk ((t&3)*8)
  const int row0 = t >> 2;              // 0..63
  const int kc0  = (t & 3) << 3;        // 0,8,16,24
  const unsigned short* gA = A  + (size_t)(bm * 128 + row0) * K_DIM + kc0;
  const unsigned short* gB = BT + (size_t)(bn * 128 + row0) * K_DIM + kc0;
  unsigned short* lA0 = &As[t * 8];
  unsigned short* lA1 = &As[2048 + t * 8];
  unsigned short* lB0 = &Bs[t * 8];
  unsigned short* lB1 = &Bs[2048 + t * 8];

  const int g = l >> 4;   // k-group 0..3
  const int r = l & 15;

  for (int kt = 0; kt < K_DIM / 32; ++kt) {
    if (kt) __syncthreads();
    const int ko = kt * 32;
    __builtin_amdgcn_global_load_lds((gq_t)(gA + ko),                     (lq_t)lA0, 16, 0, 0);
    __builtin_amdgcn_global_load_lds((gq_t)(gA + 64 * K_DIM + ko),        (lq_t)lA1, 16, 0, 0);
    __builtin_amdgcn_global_load_lds((gq_t)(gB + ko),                     (lq_t)lB0, 16, 0, 0);
    __builtin_amdgcn_global_load_lds((gq_t)(gB + 64 * K_DIM + ko),        (lq_t)lB1, 16, 0, 0);
    __syncthreads();   // compiler emits vmcnt(0) drain -> LDS tile ready

    bf16x8 af[4], bfr[4];
#pragma unroll
    for (int m = 0; m < 4; ++m) {
      int row = wr * 64 + m * 16 + r;
      af[m] = __builtin_bit_cast(bf16x8, *reinterpret_cast<const ushort8*>(&As[row * 32 + g * 8]));
    }
#pragma unroll
    for (int n = 0; n < 4; ++n) {
      int col = wc * 64 + n * 16 + r;
      bfr[n] = __builtin_bit_cast(bf16x8, *reinterpret_cast<const ushort8*>(&Bs[col * 32 + g * 8]));
    }
#pragma unroll
    for (int m = 0; m < 4; ++m)
#pragma unroll
      for (int n = 0; n < 4; ++n)
        acc[m][n] = __builtin_amdgcn_mfma_f32_16x16x32_bf16(af[m], bfr[n], acc[m][n], 0, 0, 0);
  }

  // epilogue: C/D layout col=lane&15, row=(lane>>4)*4+reg; add bias, store bf16
  const int r4 = (l >> 4) * 4;
  const int cl = l & 15;
#pragma unroll
  for (int n = 0; n < 4; ++n) {
    int col = bn * 128 + wc * 64 + n * 16 + cl;
    float badd = bc[col];
#pragma unroll
    for (int m = 0; m < 4; ++m) {
      int row = bm * 128 + wr * 64 + m * 16 + r4;
      unsigned short* out = C + (size_t)row * N_DIM + col;
#pragma unroll
      for (int i = 0; i < 4; ++i)
        out[(size_t)i * N_DIM] = f2bf(acc[m][n][i] + badd);
    }
  }
}

// ---------- SRU recurrence over a chunk of Lc steps, bf16 u planes ----------
__global__ void k_rec(const float* __restrict__ x,          // chunk base (Lc, BD) f32
                      const unsigned short* __restrict__ u3,// chunk (Lc*32, 3072) bf16 planes
                      const float* __restrict__ wcv,        // weight_c (2D)
                      const float* __restrict__ sxp,        // scale_x
                      float* __restrict__ c_state,          // (BD)
                      float* __restrict__ h,                // chunk base (Lc, BD) f32
                      int Lc)
{
  int tid = blockIdx.x * blockDim.x + threadIdx.x;
  if (tid >= BD) return;
  const int d = tid & (D_DIM - 1);
  const int b = tid >> 10;
  const float fw = wcv[d];
  const float rw = wcv[D_DIM + d];
  const float sx = sxp[0];
  float c = c_state[tid];

  // u element for (l, b, d, plane k): (l*32+b)*3072 + k*1024 + d
  const unsigned short* up = u3 + (size_t)b * N_DIM + d;
  const float* xp = x + tid;
  float*       hp = h + tid;

#pragma unroll 8
  for (int l = 0; l < Lc; ++l) {
    float u0 = bf2f(up[0]);
    float u1 = bf2f(up[1024]);
    float u2 = bf2f(up[2048]);
    float xv = xp[0] * sx;
    float f = 1.f / (1.f + __expf(-(u1 + c * fw)));
    float r = 1.f / (1.f + __expf(-(u2 + c * rw)));
    c = u0 + (c - u0) * f;
    hp[0] = xv + (c - xv) * r;
    up += (size_t)32 * N_DIM;
    xp += BD;
    hp += BD;
  }
  c_state[tid] = c;
}

__global__ void k_copyc(const float* __restrict__ c_state, float* __restrict__ out) {
  int i = blockIdx.x * blockDim.x + threadIdx.x;
  if (i < BD) out[i] = c_state[i];
}

extern "C" void kernel_launch(void* const* d_in, const int* in_sizes, int n_in,
                              void* d_out, int out_size, void* d_ws, size_t ws_size,
                              hipStream_t stream) {
  const float* x    = (const float*)d_in[0];
  const float* w    = (const float*)d_in[1];
  const float* wcv  = (const float*)d_in[2];
  const float* bias = (const float*)d_in[3];
  const float* sx   = (const float*)d_in[4];
  float* hout = (float*)d_out;
  float* cout = hout + (size_t)L_DIM * BD;

  // workspace layout
  const size_t wt_bytes = (size_t)N_DIM * K_DIM * 2;      // 6,291,456
  const size_t bc_off   = wt_bytes;
  const size_t c_off    = bc_off + (size_t)N_DIM * 4;
  const size_t xbf_off  = c_off + (size_t)BD * 4;         // 6,434,816
  int Lc = 4;
  for (int cand : {512, 256, 128, 64, 32, 16, 8}) {
    // xbf chunk: cand*BD*2 ; u3 chunk bf16: cand*BD*3*2
    size_t need = xbf_off + (size_t)cand * 65536 + (size_t)cand * 196608 + 1024;
    if (need <= ws_size) { Lc = cand; break; }
  }
  char* wsb = (char*)d_ws;
  unsigned short* wt_p  = (unsigned short*)wsb;
  float*          bc_p  = (float*)(wsb + bc_off);
  float*          c_p   = (float*)(wsb + c_off);
  unsigned short* xbf_p = (unsigned short*)(wsb + xbf_off);
  unsigned short* u3_p  = (unsigned short*)(wsb + xbf_off + (size_t)Lc * 65536);

  hipMemsetAsync(c_p, 0, (size_t)BD * 4, stream);
  k_wt<<<(K_DIM / 64) * (D_DIM / 64) * 3, 256, 0, stream>>>(w, wt_p);
  k_biascol<<<(N_DIM + 255) / 256, 256, 0, stream>>>(bias, bc_p);

  const int nchunks = L_DIM / Lc;
  const int Mtiles  = (Lc * B_DIM) / 128;
  for (int ci = 0; ci < nchunks; ++ci) {
    const size_t base = (size_t)ci * Lc * BD;
    k_convx<<<(Lc * BD / 8 + 255) / 256, 256, 0, stream>>>(x + base, xbf_p, Lc * BD / 8);
    k_gemm<<<Mtiles * (N_DIM / 128), 256, 0, stream>>>(xbf_p, wt_p, bc_p, u3_p, Mtiles);
    k_rec<<<BD / 64, 64, 0, stream>>>(x + base, u3_p, wcv, sx, c_p, hout + base, Lc);
  }
  k_copyc<<<BD / 256, 256, 0, stream>>>(c_p, cout);
}

// Round 3
// 820.437 us; speedup vs baseline: 1.4911x; 1.1552x over previous
//
#include <hip/hip_runtime.h>
#include <stdint.h>

#define L_DIM 2048
#define B_DIM 32
#define D_DIM 1024
#define N_DIM 3072   // 3*D
#define K_DIM 1024
#define BD    32768  // B*D

typedef __bf16 bf16x8 __attribute__((ext_vector_type(8)));
typedef unsigned short ushort8 __attribute__((ext_vector_type(8)));
typedef float f32x4 __attribute__((ext_vector_type(4)));

typedef const __attribute__((address_space(1))) unsigned int* gq_t;
typedef __attribute__((address_space(3))) unsigned int* lq_t;

static __device__ __forceinline__ unsigned short f2bf(float f) {
  unsigned u = __float_as_uint(f);
  u += 0x7FFFu + ((u >> 16) & 1u);   // RNE
  return (unsigned short)(u >> 16);
}

static __device__ __forceinline__ float bf2f(unsigned short s) {
  return __uint_as_float(((unsigned)s) << 16);
}

// ---------- convert x chunk (f32) -> bf16, 8 elems/thread ----------
__global__ void k_convx(const float* __restrict__ x, unsigned short* __restrict__ xb, int n8) {
  int i = blockIdx.x * blockDim.x + threadIdx.x;
  if (i >= n8) return;
  const float4* p = reinterpret_cast<const float4*>(x) + (size_t)i * 2;
  float4 a = p[0], b = p[1];
  ushort8 o;
  o[0] = f2bf(a.x); o[1] = f2bf(a.y); o[2] = f2bf(a.z); o[3] = f2bf(a.w);
  o[4] = f2bf(b.x); o[5] = f2bf(b.y); o[6] = f2bf(b.z); o[7] = f2bf(b.w);
  reinterpret_cast<ushort8*>(xb)[i] = o;
}

// ---------- W (K,N=3072 interleaved 3d+k) f32 -> WT (N'=k*D+d, K) bf16 ----------
__global__ __launch_bounds__(256) void k_wt(const float* __restrict__ w, unsigned short* __restrict__ wt) {
  __shared__ unsigned short tile[64][65];
  const int bid = blockIdx.x;
  const int kb = bid & 15;          // K/64 tile
  const int db = (bid >> 4) & 15;   // D/64 tile
  const int kp = bid >> 8;          // plane 0..2
  const int t = threadIdx.x;
  const int c = t & 63;
  const int q = t >> 6;             // 0..3
#pragma unroll
  for (int i = 0; i < 16; ++i) {
    int r = q * 16 + i;             // k within tile
    float v = w[(size_t)(kb * 64 + r) * N_DIM + 3 * (db * 64 + c) + kp];
    tile[r][c] = f2bf(v);
  }
  __syncthreads();
  const int k = t & 63;
#pragma unroll
  for (int i = 0; i < 16; ++i) {
    int n = q * 16 + i;             // d within tile
    wt[(size_t)(kp * D_DIM + db * 64 + n) * K_DIM + kb * 64 + k] = tile[k][n];
  }
}

// ---------- per-column bias, plane layout: col j = k*D+d ----------
__global__ void k_biascol(const float* __restrict__ bias, float* __restrict__ bc) {
  int j = blockIdx.x * blockDim.x + threadIdx.x;
  if (j >= N_DIM) return;
  int k = j >> 10;
  int d = j & 1023;
  float v = 0.f;
  if (k == 1) v = bias[d];
  else if (k == 2) v = bias[D_DIM + d];
  bc[j] = v;
}

// ---------- 256x256 8-phase bf16 MFMA GEMM (T1+T2+T3+T4+T5) ----------
// A (M,1024) bf16; BT (3072,1024) bf16; C (M,3072) bf16. BK=64, NT=16 K-tiles.
// 512 thr = 8 waves (2 Mx4 N); per-wave out 128x64 = acc[8][4] f32x4.
// LDS 128KiB: buf b: A at b*32768 (256x64), B at b*32768+16384.
// k-octet swizzle: LDS[row][kg] holds global k-octet kg^(row&7).
__global__ __launch_bounds__(512, 2) void k_gemm(
    const unsigned short* __restrict__ A,
    const unsigned short* __restrict__ BT,
    const float* __restrict__ bc,
    unsigned short* __restrict__ C,
    int Mtiles)
{
  __shared__ unsigned short smem[65536];

  // --- block swizzle (bijective, 8 XCDs) ---
  const int nwg = gridDim.x;
  const int q8 = nwg >> 3, r8 = nwg & 7;
  const int xcd = blockIdx.x & 7, li = blockIdx.x >> 3;
  const int wg = (xcd < r8 ? xcd * (q8 + 1) : r8 * (q8 + 1) + (xcd - r8) * q8) + li;
  const int bm = wg % Mtiles;
  const int bn = wg / Mtiles;

  const int t  = threadIdx.x;
  const int w  = t >> 6;
  const int l  = t & 63;
  const int wr = w >> 2, wc = w & 3;
  const int wrb = wr * 128, wcb = wc * 64;
  const int l15 = l & 15, lg = l >> 4, lx = l & 7;
  const int kgp0 = (lg ^ lx) * 8;          // elem offset of ksub=0 octet
  const int kgp1 = ((4 + lg) ^ lx) * 8;    // ksub=1
  // staging constants
  const int sr0 = w * 8 + (l >> 3);        // row within half (j=0)
  const int kgs = (lx ^ (l >> 3)) * 8;     // swizzled source k-octet

  const unsigned short* Abase = A  + (size_t)(bm * 256) * K_DIM;
  const unsigned short* Bbase = BT + (size_t)(bn * 256) * K_DIM;

  f32x4 acc[8][4];
#pragma unroll
  for (int i = 0; i < 8; ++i)
#pragma unroll
    for (int j = 0; j < 4; ++j) acc[i][j] = f32x4{0.f, 0.f, 0.f, 0.f};

  // stage one half-tile (128 rows x 64 k): 2 x global_load_lds(16B)
#define STAGE(G, growbase, T, ldsBase)                                                  \
  { const unsigned short* s0_ = (G) + (((size_t)((growbase) + sr0)) << 10) + (T) * 64 + kgs; \
    __builtin_amdgcn_global_load_lds((gq_t)s0_, (lq_t)&smem[(ldsBase) + w * 512], 16, 0, 0); \
    const unsigned short* s1_ = s0_ + (64 << 10);                                       \
    __builtin_amdgcn_global_load_lds((gq_t)s1_, (lq_t)&smem[(ldsBase) + 4096 + w * 512], 16, 0, 0); }

#define SB0(T, b) STAGE(Bbase, 0,   (T), (b) * 32768 + 16384)
#define SB1(T, b) STAGE(Bbase, 128, (T), (b) * 32768 + 16384 + 8192)
#define SA0(T, b) STAGE(Abase, 0,   (T), (b) * 32768)
#define SA1(T, b) STAGE(Abase, 128, (T), (b) * 32768 + 8192)

#define LDF(idx) __builtin_bit_cast(bf16x8, *reinterpret_cast<const ushort8*>(&smem[(idx)]))

  // ---- prologue: tile0 fully + SB0(1); wait tile0 (8 oldest), SB0(1) in flight
  SB0(0, 0); SB1(0, 0); SA0(0, 0); SA1(0, 0); SB0(1, 1);
  asm volatile("s_waitcnt vmcnt(2)" ::: "memory");
  __builtin_amdgcn_s_barrier();

#pragma unroll 2
  for (int t0 = 0; t0 < 16; ++t0) {
    const int cur = t0 & 1, nxt = cur ^ 1;
    const int cA = cur * 32768, cB = cA + 16384;
    bf16x8 bfr[4][2];
#pragma unroll
    for (int q = 0; q < 4; ++q) {
      bf16x8 af[2][2];
      if (q == 0) {
#pragma unroll
        for (int nf = 0; nf < 4; ++nf) {
          const int nr = (wcb + nf * 16 + l15) * 64;
          bfr[nf][0] = LDF(cB + nr + kgp0);
          bfr[nf][1] = LDF(cB + nr + kgp1);
        }
      }
#pragma unroll
      for (int mf = 0; mf < 2; ++mf) {
        const int ar = (wrb + (q * 2 + mf) * 16 + l15) * 64;
        af[mf][0] = LDF(cA + ar + kgp0);
        af[mf][1] = LDF(cA + ar + kgp1);
      }
      // staging issue (order: SB0@p4 of t-1, SB1@p1, SA0@p2, SA1@p3)
      if (q == 0 && t0 < 15) SB1(t0 + 1, nxt);
      if (q == 1 && t0 < 15) SA0(t0 + 1, nxt);
      if (q == 2 && t0 < 15) SA1(t0 + 1, nxt);
      if (q == 3 && t0 < 14) SB0(t0 + 2, cur);

      __builtin_amdgcn_s_barrier();
      __builtin_amdgcn_s_setprio(1);
#pragma unroll
      for (int mf = 0; mf < 2; ++mf)
#pragma unroll
        for (int nf = 0; nf < 4; ++nf) {
          acc[q * 2 + mf][nf] = __builtin_amdgcn_mfma_f32_16x16x32_bf16(af[mf][0], bfr[nf][0], acc[q * 2 + mf][nf], 0, 0, 0);
          acc[q * 2 + mf][nf] = __builtin_amdgcn_mfma_f32_16x16x32_bf16(af[mf][1], bfr[nf][1], acc[q * 2 + mf][nf], 0, 0, 0);
        }
      __builtin_amdgcn_s_setprio(0);
      if (q == 3) {
        if (t0 < 14)       asm volatile("s_waitcnt vmcnt(2)" ::: "memory");
        else if (t0 == 14) asm volatile("s_waitcnt vmcnt(0)" ::: "memory");
      }
      __builtin_amdgcn_s_barrier();
      __builtin_amdgcn_sched_barrier(0);
    }
  }

  // ---- epilogue: bias add, f32->bf16, store
  const int r4 = lg * 4;
  float badd[4];
#pragma unroll
  for (int nf = 0; nf < 4; ++nf) badd[nf] = bc[bn * 256 + wcb + nf * 16 + l15];
#pragma unroll
  for (int fm = 0; fm < 8; ++fm) {
    const int row = bm * 256 + wrb + fm * 16 + r4;
#pragma unroll
    for (int nf = 0; nf < 4; ++nf) {
      const int col = bn * 256 + wcb + nf * 16 + l15;
      unsigned short* out = C + (size_t)row * N_DIM + col;
#pragma unroll
      for (int i = 0; i < 4; ++i)
        out[(size_t)i * N_DIM] = f2bf(acc[fm][nf][i] + badd[nf]);
    }
  }
#undef STAGE
#undef SB0
#undef SB1
#undef SA0
#undef SA1
#undef LDF
}

// ---------- SRU recurrence over a chunk of Lc steps, bf16 u planes + bf16 x ----------
__global__ void k_rec(const unsigned short* __restrict__ xb,  // chunk (Lc, BD) bf16
                      const unsigned short* __restrict__ u3,  // chunk (Lc*32, 3072) bf16 planes
                      const float* __restrict__ wcv,
                      const float* __restrict__ sxp,
                      float* __restrict__ c_state,            // (BD)
                      float* __restrict__ h,                  // chunk base (Lc, BD) f32
                      int Lc)
{
  int tid = blockIdx.x * blockDim.x + threadIdx.x;
  if (tid >= BD) return;
  const int d = tid & (D_DIM - 1);
  const int b = tid >> 10;
  const float fw = wcv[d];
  const float rw = wcv[D_DIM + d];
  const float sx = sxp[0];
  float c = c_state[tid];

  const unsigned short* up = u3 + (size_t)b * N_DIM + d;
  const unsigned short* xp = xb + tid;
  float*                hp = h + tid;

#pragma unroll 8
  for (int l = 0; l < Lc; ++l) {
    float u0 = bf2f(up[0]);
    float u1 = bf2f(up[1024]);
    float u2 = bf2f(up[2048]);
    float xv = bf2f(xp[0]) * sx;
    float f = 1.f / (1.f + __expf(-(u1 + c * fw)));
    float r = 1.f / (1.f + __expf(-(u2 + c * rw)));
    c = u0 + (c - u0) * f;
    hp[0] = xv + (c - xv) * r;
    up += (size_t)32 * N_DIM;
    xp += BD;
    hp += BD;
  }
  c_state[tid] = c;
}

__global__ void k_copyc(const float* __restrict__ c_state, float* __restrict__ out) {
  int i = blockIdx.x * blockDim.x + threadIdx.x;
  if (i < BD) out[i] = c_state[i];
}

extern "C" void kernel_launch(void* const* d_in, const int* in_sizes, int n_in,
                              void* d_out, int out_size, void* d_ws, size_t ws_size,
                              hipStream_t stream) {
  const float* x    = (const float*)d_in[0];
  const float* w    = (const float*)d_in[1];
  const float* wcv  = (const float*)d_in[2];
  const float* bias = (const float*)d_in[3];
  const float* sx   = (const float*)d_in[4];
  float* hout = (float*)d_out;
  float* cout = hout + (size_t)L_DIM * BD;

  const size_t wt_bytes = (size_t)N_DIM * K_DIM * 2;
  const size_t bc_off   = wt_bytes;
  const size_t c_off    = bc_off + (size_t)N_DIM * 4;
  const size_t xbf_off  = c_off + (size_t)BD * 4;
  int Lc = 8;
  for (int cand : {512, 256, 128, 64, 32, 16, 8}) {
    size_t need = xbf_off + (size_t)cand * 65536 + (size_t)cand * 196608 + 1024;
    if (need <= ws_size) { Lc = cand; break; }
  }
  char* wsb = (char*)d_ws;
  unsigned short* wt_p  = (unsigned short*)wsb;
  float*          bc_p  = (float*)(wsb + bc_off);
  float*          c_p   = (float*)(wsb + c_off);
  unsigned short* xbf_p = (unsigned short*)(wsb + xbf_off);
  unsigned short* u3_p  = (unsigned short*)(wsb + xbf_off + (size_t)Lc * 65536);

  hipMemsetAsync(c_p, 0, (size_t)BD * 4, stream);
  k_wt<<<(K_DIM / 64) * (D_DIM / 64) * 3, 256, 0, stream>>>(w, wt_p);
  k_biascol<<<(N_DIM + 255) / 256, 256, 0, stream>>>(bias, bc_p);

  const int nchunks = L_DIM / Lc;
  const int Mtiles  = (Lc * B_DIM) / 256;
  for (int ci = 0; ci < nchunks; ++ci) {
    const size_t base = (size_t)ci * Lc * BD;
    k_convx<<<(Lc * BD / 8 + 255) / 256, 256, 0, stream>>>(x + base, xbf_p, Lc * BD / 8);
    k_gemm<<<Mtiles * (N_DIM / 256), 512, 0, stream>>>(xbf_p, wt_p, bc_p, u3_p, Mtiles);
    k_rec<<<BD / 64, 64, 0, stream>>>(xbf_p, u3_p, wcv, sx, c_p, hout + base, Lc);
  }
  k_copyc<<<BD / 256, 256, 0, stream>>>(c_p, cout);
}